// Round 3
// baseline (271.050 us; speedup 1.0000x reference)
//
#include <hip/hip_runtime.h>
#include <cmath>
#include <cfloat>
#include <climits>

constexpr int D    = 128;
constexpr float EPS_ = 1e-10f;
constexpr int KMAX = 64;

// =============== kernel 0: qt[b] = Wk^T (Wq t[b] + bq) ===============
__global__ __launch_bounds__(128) void proj_kernel(
    const float* __restrict__ target, const float* __restrict__ Wq,
    const float* __restrict__ bq, const float* __restrict__ Wk,
    float* __restrict__ qt)
{
  __shared__ float sTgt[D];
  __shared__ float sQ[D];
  const int b = blockIdx.x, tid = threadIdx.x;
  sTgt[tid] = target[(size_t)b * D + tid];
  __syncthreads();
  float acc = 0.f;
  const float* wrow = Wq + (size_t)tid * D;
  #pragma unroll 8
  for (int e = 0; e < D; ++e) acc += sTgt[e] * wrow[e];
  sQ[tid] = acc + bq[tid];
  __syncthreads();
  acc = 0.f;
  #pragma unroll 8
  for (int d = 0; d < D; ++d) acc += sQ[d] * Wk[(size_t)d * D + tid];
  qt[(size_t)b * D + tid] = acc;
}

// =============== kernel 1: scores[b,n] = qt[b] . cand[b,n] / sqrt(D) ===========
// Barrier-free, LDS-free streaming kernel. 16 lanes per row.
constexpr int NT1 = 256;
__global__ __launch_bounds__(NT1, 8) void score_kernel(
    const float* __restrict__ cand, const float* __restrict__ qt,
    float* __restrict__ scores, int N, int rows_per_blk)
{
  const int b    = blockIdx.x;
  const int tid  = threadIdx.x;
  const int lane = tid & 63;
  const int wave = tid >> 6;
  const int grp  = lane >> 4;
  const int gl   = lane & 15;

  const float* qp = qt + (size_t)b * D + gl * 8;
  float4 qa = ((const float4*)qp)[0];
  float4 qb = ((const float4*)qp)[1];

  const float scale = sqrtf((float)D);
  const int n0 = blockIdx.y * rows_per_blk;
  const int n1 = n0 + rows_per_blk;          // rows_per_blk % 32 == 0
  const float* base = cand + (size_t)b * N * D;
  float* srow = scores + (size_t)b * N;

  for (int n = n0 + wave * 4 + grp; n < n1; n += 32) {
    const float4* r0 = (const float4*)(base + (size_t)n * D);
    const float4* r1 = (const float4*)(base + (size_t)(n + 16) * D);
    float4 a0 = r0[gl * 2 + 0];
    float4 a1 = r0[gl * 2 + 1];
    float4 c0 = r1[gl * 2 + 0];
    float4 c1 = r1[gl * 2 + 1];
    float p0 = a0.x * qa.x + a0.y * qa.y + a0.z * qa.z + a0.w * qa.w
             + a1.x * qb.x + a1.y * qb.y + a1.z * qb.z + a1.w * qb.w;
    float p1 = c0.x * qa.x + c0.y * qa.y + c0.z * qa.z + c0.w * qa.w
             + c1.x * qb.x + c1.y * qb.y + c1.z * qb.z + c1.w * qb.w;
    p0 += __shfl_xor(p0, 1);  p1 += __shfl_xor(p1, 1);
    p0 += __shfl_xor(p0, 2);  p1 += __shfl_xor(p1, 2);
    p0 += __shfl_xor(p0, 4);  p1 += __shfl_xor(p1, 4);
    p0 += __shfl_xor(p0, 8);  p1 += __shfl_xor(p1, 8);
    if (gl == 0) { srow[n] = p0 / scale; srow[n + 16] = p1 / scale; }
  }
}

// =============== kernel 2: per-row softmax + gumbel + top-k ===============
// 256 threads (4 waves); N must equal 2048. All values in registers.
constexpr int NT2 = 256;
__global__ __launch_bounds__(NT2) void topk_kernel(
    const float* __restrict__ scores, const float* __restrict__ u,
    const int* __restrict__ kptr, int* __restrict__ out, int N)
{
  __shared__ float redM[4];
  __shared__ float redS[4];
  __shared__ float cV[4 * KMAX];
  __shared__ int   cI[4 * KMAX];

  const int b    = blockIdx.x;
  const int tid  = threadIdx.x;
  const int lane = tid & 63;
  const int wave = tid >> 6;
  const int base = wave * 512 + lane * 8;   // this lane's 8 contiguous elems

  const float* srow = scores + (size_t)b * N;
  float4 s0 = ((const float4*)(srow + base))[0];
  float4 s1 = ((const float4*)(srow + base))[1];
  float v[8] = { s0.x, s0.y, s0.z, s0.w, s1.x, s1.y, s1.z, s1.w };

  // ---- row max ----
  float m = v[0];
  #pragma unroll
  for (int j = 1; j < 8; ++j) m = fmaxf(m, v[j]);
  for (int s = 32; s; s >>= 1) m = fmaxf(m, __shfl_xor(m, s));
  if (lane == 0) redM[wave] = m;
  __syncthreads();
  m = fmaxf(fmaxf(redM[0], redM[1]), fmaxf(redM[2], redM[3]));

  // ---- sum of exp ----
  float ssum = 0.f;
  #pragma unroll
  for (int j = 0; j < 8; ++j) ssum += expf(v[j] - m);
  for (int s = 32; s; s >>= 1) ssum += __shfl_xor(ssum, s);
  if (lane == 0) redS[wave] = ssum;
  __syncthreads();
  const float Z = redS[0] + redS[1] + redS[2] + redS[3];

  // ---- values: log(0.9*softmax + 0.1/N) + gumbel ----
  const float mixc = (float)(0.1 / (double)N);
  const float* urow = u + (size_t)b * N;
  float4 u0 = ((const float4*)(urow + base))[0];
  float4 u1 = ((const float4*)(urow + base))[1];
  float uu[8] = { u0.x, u0.y, u0.z, u0.w, u1.x, u1.y, u1.z, u1.w };
  #pragma unroll
  for (int j = 0; j < 8; ++j) {
    float pmix = 0.9f * (expf(v[j] - m) / Z) + mixc;
    float g = -logf(-logf(uu[j] + EPS_) + EPS_);
    v[j] = logf(pmix) + g;
  }

  const int k = kptr[0];

  // ---- wave-local top-k (shuffle-only, no barriers) ----
  for (int i = 0; i < k; ++i) {
    float bv = v[0]; int bj = 0;
    #pragma unroll
    for (int j = 1; j < 8; ++j) if (v[j] > bv) { bv = v[j]; bj = j; }  // lower j wins ties
    int bidx = base + bj;
    for (int s = 32; s; s >>= 1) {
      float ov = __shfl_xor(bv, s);
      int   oi = __shfl_xor(bidx, s);
      if (ov > bv || (ov == bv && oi < bidx)) { bv = ov; bidx = oi; }
    }
    // winner lane clears its register (static indexing only)
    if (lane == ((bidx - wave * 512) >> 3)) {
      int off = bidx & 7;
      #pragma unroll
      for (int j = 0; j < 8; ++j) if (off == j) v[j] = -FLT_MAX;
    }
    if (lane == 0) { cV[wave * KMAX + i] = bv; cI[wave * KMAX + i] = bidx; }
  }
  __syncthreads();

  // ---- merge 4*k candidates on wave 0 ----
  if (wave == 0) {
    const int tot = 4 * k;                 // <= 256
    float mv[4]; int mi[4];
    #pragma unroll
    for (int t = 0; t < 4; ++t) {
      int c = lane + 64 * t;
      if (c < tot) {
        int w = c / k, i = c % k;
        mv[t] = cV[w * KMAX + i]; mi[t] = cI[w * KMAX + i];
      } else { mv[t] = -FLT_MAX; mi[t] = INT_MAX; }
    }
    for (int i = 0; i < k; ++i) {
      float bv = mv[0]; int bidx = mi[0];
      #pragma unroll
      for (int t = 1; t < 4; ++t)
        if (mv[t] > bv || (mv[t] == bv && mi[t] < bidx)) { bv = mv[t]; bidx = mi[t]; }
      for (int s = 32; s; s >>= 1) {
        float ov = __shfl_xor(bv, s);
        int   oi = __shfl_xor(bidx, s);
        if (ov > bv || (ov == bv && oi < bidx)) { bv = ov; bidx = oi; }
      }
      #pragma unroll
      for (int t = 0; t < 4; ++t) if (mi[t] == bidx) mv[t] = -FLT_MAX;
      if (lane == 0) out[(size_t)b * k + i] = bidx;
    }
  }
}

// =============== fallback: R2 fused kernel (used if ws too small) ===============
constexpr int NTF = 512;
constexpr int NWF = NTF / 64;
__global__ __launch_bounds__(NTF, 8) void fused_kernel(
    const float* __restrict__ target, const float* __restrict__ cand,
    const float* __restrict__ Wq, const float* __restrict__ bq,
    const float* __restrict__ Wk, const float* __restrict__ u,
    const int* __restrict__ kptr, int* __restrict__ out, int N)
{
  extern __shared__ float sS[];
  __shared__ float sTgt[D];
  __shared__ float sQ[D];
  __shared__ float sQt[D];
  __shared__ float redV[NWF];
  __shared__ int   redI[NWF];

  const int b = blockIdx.x, tid = threadIdx.x;
  const int lane = tid & 63, wave = tid >> 6;

  if (tid < D) sTgt[tid] = target[(size_t)b * D + tid];
  __syncthreads();
  if (tid < D) {
    float acc = 0.f;
    const float* wrow = Wq + (size_t)tid * D;
    #pragma unroll 8
    for (int e = 0; e < D; ++e) acc += sTgt[e] * wrow[e];
    sQ[tid] = acc + bq[tid];
  }
  __syncthreads();
  if (tid < D) {
    float acc = 0.f;
    #pragma unroll 8
    for (int d = 0; d < D; ++d) acc += sQ[d] * Wk[(size_t)d * D + tid];
    sQt[tid] = acc;
  }
  __syncthreads();

  const int grp = lane >> 4, gl = lane & 15;
  float q0 = sQt[gl*8+0], q1 = sQt[gl*8+1], q2 = sQt[gl*8+2], q3 = sQt[gl*8+3];
  float q4 = sQt[gl*8+4], q5 = sQt[gl*8+5], q6 = sQt[gl*8+6], q7 = sQt[gl*8+7];
  const float scale = sqrtf((float)D);
  const int rstride = NWF * 4;
  int n = wave * 4 + grp;
  for (; n + rstride < N; n += 2 * rstride) {
    const float4* r0 = (const float4*)(cand + ((size_t)b * N + n) * D);
    const float4* r1 = (const float4*)(cand + ((size_t)b * N + n + rstride) * D);
    float4 a0 = r0[gl*2+0], a1 = r0[gl*2+1], c0 = r1[gl*2+0], c1 = r1[gl*2+1];
    float p0 = a0.x*q0 + a0.y*q1 + a0.z*q2 + a0.w*q3 + a1.x*q4 + a1.y*q5 + a1.z*q6 + a1.w*q7;
    float p1 = c0.x*q0 + c0.y*q1 + c0.z*q2 + c0.w*q3 + c1.x*q4 + c1.y*q5 + c1.z*q6 + c1.w*q7;
    p0 += __shfl_xor(p0,1); p1 += __shfl_xor(p1,1);
    p0 += __shfl_xor(p0,2); p1 += __shfl_xor(p1,2);
    p0 += __shfl_xor(p0,4); p1 += __shfl_xor(p1,4);
    p0 += __shfl_xor(p0,8); p1 += __shfl_xor(p1,8);
    if (gl == 0) { sS[n] = p0 / scale; sS[n + rstride] = p1 / scale; }
  }
  if (n < N) {
    const float4* r0 = (const float4*)(cand + ((size_t)b * N + n) * D);
    float4 a0 = r0[gl*2+0], a1 = r0[gl*2+1];
    float p0 = a0.x*q0 + a0.y*q1 + a0.z*q2 + a0.w*q3 + a1.x*q4 + a1.y*q5 + a1.z*q6 + a1.w*q7;
    p0 += __shfl_xor(p0,1); p0 += __shfl_xor(p0,2); p0 += __shfl_xor(p0,4); p0 += __shfl_xor(p0,8);
    if (gl == 0) sS[n] = p0 / scale;
  }
  __syncthreads();

  float m = -FLT_MAX;
  for (int i = tid; i < N; i += NTF) m = fmaxf(m, sS[i]);
  for (int s = 32; s; s >>= 1) m = fmaxf(m, __shfl_xor(m, s));
  if (lane == 0) redV[wave] = m;
  __syncthreads();
  m = redV[0];
  #pragma unroll
  for (int w = 1; w < NWF; ++w) m = fmaxf(m, redV[w]);
  __syncthreads();

  float ssum = 0.f;
  for (int i = tid; i < N; i += NTF) ssum += expf(sS[i] - m);
  for (int s = 32; s; s >>= 1) ssum += __shfl_xor(ssum, s);
  if (lane == 0) redV[wave] = ssum;
  __syncthreads();
  float Z = redV[0];
  #pragma unroll
  for (int w = 1; w < NWF; ++w) Z += redV[w];
  __syncthreads();

  const float mixc = (float)(0.1 / (double)N);
  for (int i = tid; i < N; i += NTF) {
    float pmix = 0.9f * (expf(sS[i] - m) / Z) + mixc;
    float uv = u[(size_t)b * N + i];
    float g = -logf(-logf(uv + EPS_) + EPS_);
    sS[i] = logf(pmix) + g;
  }
  __syncthreads();

  const int k = kptr[0];
  for (int i = 0; i < k; ++i) {
    float bv = -FLT_MAX; int bi = N;
    for (int j = tid; j < N; j += NTF) {
      float vv = sS[j];
      if (vv > bv || (vv == bv && j < bi)) { bv = vv; bi = j; }
    }
    for (int s = 32; s; s >>= 1) {
      float ov = __shfl_xor(bv, s); int oi = __shfl_xor(bi, s);
      if (ov > bv || (ov == bv && oi < bi)) { bv = ov; bi = oi; }
    }
    if (lane == 0) { redV[wave] = bv; redI[wave] = bi; }
    __syncthreads();
    if (tid == 0) {
      float fv = redV[0]; int fi = redI[0];
      #pragma unroll
      for (int w = 1; w < NWF; ++w)
        if (redV[w] > fv || (redV[w] == fv && redI[w] < fi)) { fv = redV[w]; fi = redI[w]; }
      out[(size_t)b * k + i] = fi;
      sS[fi] = -FLT_MAX;
    }
    __syncthreads();
  }
}

extern "C" void kernel_launch(void* const* d_in, const int* in_sizes, int n_in,
                              void* d_out, int out_size, void* d_ws, size_t ws_size,
                              hipStream_t stream) {
  const float* target = (const float*)d_in[0];
  const float* cand   = (const float*)d_in[1];
  const float* Wq     = (const float*)d_in[2];
  const float* bq     = (const float*)d_in[3];
  const float* Wk     = (const float*)d_in[4];
  const float* bk     = (const float*)d_in[5];  // cancels in softmax
  const float* u      = (const float*)d_in[6];
  const int*   kptr   = (const int*)d_in[7];
  (void)bk; (void)n_in;

  const int B = in_sizes[0] / D;
  const int N = in_sizes[1] / (B * D);
  const int k = out_size / B;

  const size_t need = ((size_t)B * N + (size_t)B * D) * sizeof(float);
  const bool ok3 = (ws_size >= need) && (N == NT2 * 8) && (k <= KMAX) &&
                   (N % 128 == 0);

  if (ok3) {
    float* scores = (float*)d_ws;
    float* qt     = scores + (size_t)B * N;
    proj_kernel<<<B, 128, 0, stream>>>(target, Wq, bq, Wk, qt);
    const int chunks = 4;
    const int rows_per_blk = N / chunks;   // 512, % 32 == 0
    score_kernel<<<dim3(B, chunks), NT1, 0, stream>>>(cand, qt, scores, N, rows_per_blk);
    topk_kernel<<<B, NT2, 0, stream>>>(scores, u, kptr, (int*)d_out, N);
  } else {
    fused_kernel<<<B, NTF, N * sizeof(float), stream>>>(
        target, cand, Wq, bq, Wk, u, kptr, (int*)d_out, N);
  }
}

// Round 4
// 246.345 us; speedup vs baseline: 1.1003x; 1.1003x over previous
//
#include <hip/hip_runtime.h>
#include <cmath>
#include <cfloat>
#include <climits>

constexpr int D    = 128;
constexpr int NT   = 512;          // 8 waves
constexpr int NW   = NT / 64;
constexpr int KMAX = 64;
constexpr float EPS_ = 1e-10f;

// ================= specialized fused kernel: N == NT*4, N%64==0 =================
__global__ __launch_bounds__(NT, 8) void fused2_kernel(
    const float* __restrict__ target, const float* __restrict__ cand,
    const float* __restrict__ Wq, const float* __restrict__ bq,
    const float* __restrict__ Wk, const float* __restrict__ u,
    const int* __restrict__ kptr, int* __restrict__ out, int N)
{
  extern __shared__ __align__(16) float sS[];   // N floats
  __shared__ __align__(16) float sTgt[D];
  __shared__ __align__(16) float sQ[D];
  __shared__ __align__(16) float sQt[D];
  __shared__ float redM[NW];
  __shared__ float cV[NW * KMAX];
  __shared__ int   cI[NW * KMAX];

  const int b    = blockIdx.x;
  const int tid  = threadIdx.x;
  const int lane = tid & 63;
  const int wave = tid >> 6;

  // ---- projections: qt = Wk^T (Wq t + bq); bk cancels in softmax ----
  if (tid < D) sTgt[tid] = target[(size_t)b * D + tid];
  __syncthreads();
  if (tid < D) {
    float acc = 0.f;
    const float* wrow = Wq + (size_t)tid * D;
    #pragma unroll 8
    for (int e = 0; e < D; ++e) acc += sTgt[e] * wrow[e];
    sQ[tid] = acc + bq[tid];
  }
  __syncthreads();
  if (tid < D) {
    float acc = 0.f;
    #pragma unroll 8
    for (int d = 0; d < D; ++d) acc += sQ[d] * Wk[(size_t)d * D + tid];
    sQt[tid] = acc;
  }
  __syncthreads();

  // ---- sweep: 32 lanes per row, fully-contiguous 1KB per load instruction ----
  const int p    = lane & 31;        // 16B-granule index within row
  const int half = lane >> 5;        // which of the 2 rows this load covers
  const float4 qf = ((const float4*)sQt)[p];
  const float inv_scale = 1.0f / sqrtf((float)D);
  const float* base = cand + (size_t)b * N * D;

  for (int n0 = wave * 8; n0 < N; n0 += NW * 8) {
    // 4 loads, each covering 2 contiguous rows (1KB span, lane*16B)
    const float4* r0 = (const float4*)(base + (size_t)(n0 + 0) * D) + lane;
    const float4* r1 = (const float4*)(base + (size_t)(n0 + 2) * D) + lane;
    const float4* r2 = (const float4*)(base + (size_t)(n0 + 4) * D) + lane;
    const float4* r3 = (const float4*)(base + (size_t)(n0 + 6) * D) + lane;
    float4 a0 = *r0, a1 = *r1, a2 = *r2, a3 = *r3;
    float s0 = a0.x * qf.x + a0.y * qf.y + a0.z * qf.z + a0.w * qf.w;
    float s1 = a1.x * qf.x + a1.y * qf.y + a1.z * qf.z + a1.w * qf.w;
    float s2 = a2.x * qf.x + a2.y * qf.y + a2.z * qf.z + a2.w * qf.w;
    float s3 = a3.x * qf.x + a3.y * qf.y + a3.z * qf.z + a3.w * qf.w;
    // 5-level butterfly within each 32-lane half; 4 independent chains
    s0 += __shfl_xor(s0, 1);  s1 += __shfl_xor(s1, 1);
    s2 += __shfl_xor(s2, 1);  s3 += __shfl_xor(s3, 1);
    s0 += __shfl_xor(s0, 2);  s1 += __shfl_xor(s1, 2);
    s2 += __shfl_xor(s2, 2);  s3 += __shfl_xor(s3, 2);
    s0 += __shfl_xor(s0, 4);  s1 += __shfl_xor(s1, 4);
    s2 += __shfl_xor(s2, 4);  s3 += __shfl_xor(s3, 4);
    s0 += __shfl_xor(s0, 8);  s1 += __shfl_xor(s1, 8);
    s2 += __shfl_xor(s2, 8);  s3 += __shfl_xor(s3, 8);
    s0 += __shfl_xor(s0, 16); s1 += __shfl_xor(s1, 16);
    s2 += __shfl_xor(s2, 16); s3 += __shfl_xor(s3, 16);
    if (p == 0) {
      sS[n0 + 0 + half] = s0 * inv_scale;
      sS[n0 + 2 + half] = s1 * inv_scale;
      sS[n0 + 4 + half] = s2 * inv_scale;
      sS[n0 + 6 + half] = s3 * inv_scale;
    }
  }
  __syncthreads();

  // ---- each thread owns 4 contiguous values ----
  const int iv = wave * 256 + lane * 4;
  float4 sv = *(const float4*)(sS + iv);
  float v0 = sv.x, v1 = sv.y, v2 = sv.z, v3 = sv.w;

  // row max
  float m = fmaxf(fmaxf(v0, v1), fmaxf(v2, v3));
  for (int s = 32; s; s >>= 1) m = fmaxf(m, __shfl_xor(m, s));
  if (lane == 0) redM[wave] = m;
  __syncthreads();
  m = redM[0];
  #pragma unroll
  for (int w = 1; w < NW; ++w) m = fmaxf(m, redM[w]);
  __syncthreads();

  // sum of exp
  float ssum = expf(v0 - m) + expf(v1 - m) + expf(v2 - m) + expf(v3 - m);
  for (int s = 32; s; s >>= 1) ssum += __shfl_xor(ssum, s);
  if (lane == 0) redM[wave] = ssum;
  __syncthreads();
  float Z = redM[0];
  #pragma unroll
  for (int w = 1; w < NW; ++w) Z += redM[w];
  __syncthreads();

  // values: log(0.9*softmax + 0.1/N) + gumbel
  const float mixc = (float)(0.1 / (double)N);
  float4 uv = *(const float4*)(u + (size_t)b * N + iv);
  v0 = logf(0.9f * (expf(v0 - m) / Z) + mixc) + (-logf(-logf(uv.x + EPS_) + EPS_));
  v1 = logf(0.9f * (expf(v1 - m) / Z) + mixc) + (-logf(-logf(uv.y + EPS_) + EPS_));
  v2 = logf(0.9f * (expf(v2 - m) / Z) + mixc) + (-logf(-logf(uv.z + EPS_) + EPS_));
  v3 = logf(0.9f * (expf(v3 - m) / Z) + mixc) + (-logf(-logf(uv.w + EPS_) + EPS_));

  const int k = kptr[0];

  // ---- wave-local top-k (registers + shuffles only) ----
  for (int i = 0; i < k; ++i) {
    float bv = v0; int bj = 0;
    if (v1 > bv) { bv = v1; bj = 1; }
    if (v2 > bv) { bv = v2; bj = 2; }
    if (v3 > bv) { bv = v3; bj = 3; }
    int bidx = iv + bj;
    for (int s = 32; s; s >>= 1) {
      float ov = __shfl_xor(bv, s);
      int   oi = __shfl_xor(bidx, s);
      if (ov > bv || (ov == bv && oi < bidx)) { bv = ov; bidx = oi; }
    }
    if (lane == ((bidx & 255) >> 2)) {       // winner lane clears (static idx)
      int off = bidx & 3;
      if (off == 0) v0 = -FLT_MAX;
      if (off == 1) v1 = -FLT_MAX;
      if (off == 2) v2 = -FLT_MAX;
      if (off == 3) v3 = -FLT_MAX;
    }
    if (lane == 0) { cV[wave * KMAX + i] = bv; cI[wave * KMAX + i] = bidx; }
  }
  __syncthreads();

  // ---- merge NW*k candidates on wave 0 ----
  if (wave == 0) {
    const int tot = NW * k;                  // <= 512
    float mv[8]; int mi[8];
    #pragma unroll
    for (int t = 0; t < 8; ++t) {
      int c = lane + 64 * t;
      if (c < tot) {
        int w = c / k, i = c % k;
        mv[t] = cV[w * KMAX + i]; mi[t] = cI[w * KMAX + i];
      } else { mv[t] = -FLT_MAX; mi[t] = INT_MAX; }
    }
    for (int i = 0; i < k; ++i) {
      float bv = mv[0]; int bidx = mi[0];
      #pragma unroll
      for (int t = 1; t < 8; ++t)
        if (mv[t] > bv || (mv[t] == bv && mi[t] < bidx)) { bv = mv[t]; bidx = mi[t]; }
      for (int s = 32; s; s >>= 1) {
        float ov = __shfl_xor(bv, s);
        int   oi = __shfl_xor(bidx, s);
        if (ov > bv || (ov == bv && oi < bidx)) { bv = ov; bidx = oi; }
      }
      #pragma unroll
      for (int t = 0; t < 8; ++t) if (mi[t] == bidx) mv[t] = -FLT_MAX;
      if (lane == 0) out[(size_t)b * k + i] = bidx;
    }
  }
}

// =============== fallback: generic fused kernel (R1 structure) ===============
constexpr int NTF = 512;
constexpr int NWF = NTF / 64;
__global__ __launch_bounds__(NTF, 8) void fused_kernel(
    const float* __restrict__ target, const float* __restrict__ cand,
    const float* __restrict__ Wq, const float* __restrict__ bq,
    const float* __restrict__ Wk, const float* __restrict__ u,
    const int* __restrict__ kptr, int* __restrict__ out, int N)
{
  extern __shared__ float sS[];
  __shared__ float sTgt[D];
  __shared__ float sQ[D];
  __shared__ float sQt[D];
  __shared__ float redV[NWF];
  __shared__ int   redI[NWF];

  const int b = blockIdx.x, tid = threadIdx.x;
  const int lane = tid & 63, wave = tid >> 6;

  if (tid < D) sTgt[tid] = target[(size_t)b * D + tid];
  __syncthreads();
  if (tid < D) {
    float acc = 0.f;
    const float* wrow = Wq + (size_t)tid * D;
    #pragma unroll 8
    for (int e = 0; e < D; ++e) acc += sTgt[e] * wrow[e];
    sQ[tid] = acc + bq[tid];
  }
  __syncthreads();
  if (tid < D) {
    float acc = 0.f;
    #pragma unroll 8
    for (int d = 0; d < D; ++d) acc += sQ[d] * Wk[(size_t)d * D + tid];
    sQt[tid] = acc;
  }
  __syncthreads();

  const int grp = lane >> 4, gl = lane & 15;
  float q0 = sQt[gl*8+0], q1 = sQt[gl*8+1], q2 = sQt[gl*8+2], q3 = sQt[gl*8+3];
  float q4 = sQt[gl*8+4], q5 = sQt[gl*8+5], q6 = sQt[gl*8+6], q7 = sQt[gl*8+7];
  const float scale = sqrtf((float)D);
  const int rstride = NWF * 4;
  int n = wave * 4 + grp;
  for (; n + rstride < N; n += 2 * rstride) {
    const float4* r0 = (const float4*)(cand + ((size_t)b * N + n) * D);
    const float4* r1 = (const float4*)(cand + ((size_t)b * N + n + rstride) * D);
    float4 a0 = r0[gl*2+0], a1 = r0[gl*2+1], c0 = r1[gl*2+0], c1 = r1[gl*2+1];
    float p0 = a0.x*q0 + a0.y*q1 + a0.z*q2 + a0.w*q3 + a1.x*q4 + a1.y*q5 + a1.z*q6 + a1.w*q7;
    float p1 = c0.x*q0 + c0.y*q1 + c0.z*q2 + c0.w*q3 + c1.x*q4 + c1.y*q5 + c1.z*q6 + c1.w*q7;
    p0 += __shfl_xor(p0,1); p1 += __shfl_xor(p1,1);
    p0 += __shfl_xor(p0,2); p1 += __shfl_xor(p1,2);
    p0 += __shfl_xor(p0,4); p1 += __shfl_xor(p1,4);
    p0 += __shfl_xor(p0,8); p1 += __shfl_xor(p1,8);
    if (gl == 0) { sS[n] = p0 / scale; sS[n + rstride] = p1 / scale; }
  }
  if (n < N) {
    const float4* r0 = (const float4*)(cand + ((size_t)b * N + n) * D);
    float4 a0 = r0[gl*2+0], a1 = r0[gl*2+1];
    float p0 = a0.x*q0 + a0.y*q1 + a0.z*q2 + a0.w*q3 + a1.x*q4 + a1.y*q5 + a1.z*q6 + a1.w*q7;
    p0 += __shfl_xor(p0,1); p0 += __shfl_xor(p0,2); p0 += __shfl_xor(p0,4); p0 += __shfl_xor(p0,8);
    if (gl == 0) sS[n] = p0 / scale;
  }
  __syncthreads();

  float m = -FLT_MAX;
  for (int i = tid; i < N; i += NTF) m = fmaxf(m, sS[i]);
  for (int s = 32; s; s >>= 1) m = fmaxf(m, __shfl_xor(m, s));
  if (lane == 0) redV[wave] = m;
  __syncthreads();
  m = redV[0];
  #pragma unroll
  for (int w = 1; w < NWF; ++w) m = fmaxf(m, redV[w]);
  __syncthreads();

  float ssum = 0.f;
  for (int i = tid; i < N; i += NTF) ssum += expf(sS[i] - m);
  for (int s = 32; s; s >>= 1) ssum += __shfl_xor(ssum, s);
  if (lane == 0) redV[wave] = ssum;
  __syncthreads();
  float Z = redV[0];
  #pragma unroll
  for (int w = 1; w < NWF; ++w) Z += redV[w];
  __syncthreads();

  const float mixc = (float)(0.1 / (double)N);
  for (int i = tid; i < N; i += NTF) {
    float pmix = 0.9f * (expf(sS[i] - m) / Z) + mixc;
    float uvs = u[(size_t)b * N + i];
    float g = -logf(-logf(uvs + EPS_) + EPS_);
    sS[i] = logf(pmix) + g;
  }
  __syncthreads();

  const int k = kptr[0];
  for (int i = 0; i < k; ++i) {
    float bv = -FLT_MAX; int bi = N;
    for (int j = tid; j < N; j += NTF) {
      float vv = sS[j];
      if (vv > bv || (vv == bv && j < bi)) { bv = vv; bi = j; }
    }
    for (int s = 32; s; s >>= 1) {
      float ov = __shfl_xor(bv, s); int oi = __shfl_xor(bi, s);
      if (ov > bv || (ov == bv && oi < bi)) { bv = ov; bi = oi; }
    }
    if (lane == 0) { redV[wave] = bv; redI[wave] = bi; }
    __syncthreads();
    if (tid == 0) {
      float fv = redV[0]; int fi = redI[0];
      #pragma unroll
      for (int w = 1; w < NWF; ++w)
        if (redV[w] > fv || (redV[w] == fv && redI[w] < fi)) { fv = redV[w]; fi = redI[w]; }
      out[(size_t)b * k + i] = fi;
      sS[fi] = -FLT_MAX;
    }
    __syncthreads();
  }
}

extern "C" void kernel_launch(void* const* d_in, const int* in_sizes, int n_in,
                              void* d_out, int out_size, void* d_ws, size_t ws_size,
                              hipStream_t stream) {
  const float* target = (const float*)d_in[0];
  const float* cand   = (const float*)d_in[1];
  const float* Wq     = (const float*)d_in[2];
  const float* bq     = (const float*)d_in[3];
  const float* Wk     = (const float*)d_in[4];
  const float* bk     = (const float*)d_in[5];  // cancels in softmax
  const float* u      = (const float*)d_in[6];
  const int*   kptr   = (const int*)d_in[7];
  (void)bk; (void)n_in; (void)d_ws; (void)ws_size;

  const int B = in_sizes[0] / D;
  const int N = in_sizes[1] / (B * D);
  const int k = out_size / B;

  if (N == NT * 4 && (N % 64) == 0 && k <= KMAX) {
    fused2_kernel<<<B, NT, N * sizeof(float), stream>>>(
        target, cand, Wq, bq, Wk, u, kptr, (int*)d_out, N);
  } else {
    fused_kernel<<<B, NTF, N * sizeof(float), stream>>>(
        target, cand, Wq, bq, Wk, u, kptr, (int*)d_out, N);
  }
}

// Round 5
// 245.904 us; speedup vs baseline: 1.1023x; 1.0018x over previous
//
#include <hip/hip_runtime.h>
#include <cmath>
#include <cfloat>
#include <climits>

constexpr int D    = 128;
constexpr int NT   = 512;          // 8 waves
constexpr int NW   = NT / 64;
constexpr int KMAX = 64;
constexpr float EPS_ = 1e-10f;

// ---------- DPP helpers (VALU-only cross-lane) ----------
// ROW_SHR:k = 0x110+k, ROW_BCAST15 = 0x142, ROW_BCAST31 = 0x143
template <int CTRL>
__device__ __forceinline__ float dpp_add(float x) {
  int y = __builtin_amdgcn_update_dpp(0, __float_as_int(x), CTRL, 0xf, 0xf, false);
  return x + __int_as_float(y);
}
template <int CTRL>
__device__ __forceinline__ float dpp_max(float x) {
  // old = self: invalid source lanes contribute x (identity for max)
  int y = __builtin_amdgcn_update_dpp(__float_as_int(x), __float_as_int(x),
                                      CTRL, 0xf, 0xf, false);
  return fmaxf(x, __int_as_float(y));
}
// sum within each 16-lane row -> lane15/31/47/63; then bcast15 -> lane31/63 = 32-lane sums
__device__ __forceinline__ float dpp_sum32(float x) {
  x = dpp_add<0x111>(x);
  x = dpp_add<0x112>(x);
  x = dpp_add<0x114>(x);
  x = dpp_add<0x118>(x);
  x = dpp_add<0x142>(x);
  return x;                        // valid in lanes 31 and 63
}
__device__ __forceinline__ float dpp_sum64(float x) {
  x = dpp_sum32(x);
  x = dpp_add<0x143>(x);           // lane63 = full-wave sum
  return __int_as_float(__builtin_amdgcn_readlane(__float_as_int(x), 63));
}
__device__ __forceinline__ float dpp_max64(float x) {
  x = dpp_max<0x111>(x);
  x = dpp_max<0x112>(x);
  x = dpp_max<0x114>(x);
  x = dpp_max<0x118>(x);
  x = dpp_max<0x142>(x);
  x = dpp_max<0x143>(x);
  return __int_as_float(__builtin_amdgcn_readlane(__float_as_int(x), 63));
}

// ================= specialized fused kernel: N == NT*4 =================
__global__ __launch_bounds__(NT, 8) void fused2_kernel(
    const float* __restrict__ target, const float* __restrict__ cand,
    const float* __restrict__ Wq, const float* __restrict__ bq,
    const float* __restrict__ Wk, const float* __restrict__ u,
    const int* __restrict__ kptr, int* __restrict__ out, int N)
{
  extern __shared__ __align__(16) float sS[];   // N floats
  __shared__ __align__(16) float sTgt[D];
  __shared__ __align__(16) float sQ[D];
  __shared__ __align__(16) float sQt[D];
  __shared__ float redM[NW];
  __shared__ float cV[NW * KMAX];
  __shared__ int   cI[NW * KMAX];

  const int b    = blockIdx.x;
  const int tid  = threadIdx.x;
  const int lane = tid & 63;
  const int wave = tid >> 6;

  // ---- projections: qt = Wk^T (Wq t + bq); bk cancels in softmax ----
  if (tid < D) sTgt[tid] = target[(size_t)b * D + tid];
  __syncthreads();
  if (tid < D) {
    float acc = 0.f;
    const float* wrow = Wq + (size_t)tid * D;
    #pragma unroll 8
    for (int e = 0; e < D; ++e) acc += sTgt[e] * wrow[e];
    sQ[tid] = acc + bq[tid];
  }
  __syncthreads();
  if (tid < D) {
    float acc = 0.f;
    #pragma unroll 8
    for (int d = 0; d < D; ++d) acc += sQ[d] * Wk[(size_t)d * D + tid];
    sQt[tid] = acc;
  }
  __syncthreads();

  // ---- sweep: contiguous 1KB per load instruction; DPP reduce (no LDS pipe) ----
  const int p    = lane & 31;        // 16B-granule index within row
  const int half = lane >> 5;        // which of the 2 rows this load covers
  const float4 qf = ((const float4*)sQt)[p];
  const float inv_scale = 1.0f / sqrtf((float)D);
  const float* base = cand + (size_t)b * N * D;
  const bool writer = (p == 31);     // lanes 31 and 63 hold the row sums

  for (int n0 = wave * 8; n0 < N; n0 += NW * 8) {
    const float4* r0 = (const float4*)(base + (size_t)(n0 + 0) * D) + lane;
    const float4* r1 = (const float4*)(base + (size_t)(n0 + 2) * D) + lane;
    const float4* r2 = (const float4*)(base + (size_t)(n0 + 4) * D) + lane;
    const float4* r3 = (const float4*)(base + (size_t)(n0 + 6) * D) + lane;
    float4 a0 = *r0, a1 = *r1, a2 = *r2, a3 = *r3;
    float s0 = a0.x * qf.x + a0.y * qf.y + a0.z * qf.z + a0.w * qf.w;
    float s1 = a1.x * qf.x + a1.y * qf.y + a1.z * qf.z + a1.w * qf.w;
    float s2 = a2.x * qf.x + a2.y * qf.y + a2.z * qf.z + a2.w * qf.w;
    float s3 = a3.x * qf.x + a3.y * qf.y + a3.z * qf.z + a3.w * qf.w;
    s0 = dpp_sum32(s0);
    s1 = dpp_sum32(s1);
    s2 = dpp_sum32(s2);
    s3 = dpp_sum32(s3);
    if (writer) {
      sS[n0 + 0 + half] = s0 * inv_scale;
      sS[n0 + 2 + half] = s1 * inv_scale;
      sS[n0 + 4 + half] = s2 * inv_scale;
      sS[n0 + 6 + half] = s3 * inv_scale;
    }
  }
  __syncthreads();

  // ---- each thread owns 4 contiguous values ----
  const int iv = wave * 256 + lane * 4;
  float4 sv = *(const float4*)(sS + iv);
  float v0 = sv.x, v1 = sv.y, v2 = sv.z, v3 = sv.w;

  // row max (DPP wave reduce + LDS combine)
  float m = fmaxf(fmaxf(v0, v1), fmaxf(v2, v3));
  m = dpp_max64(m);
  if (lane == 0) redM[wave] = m;
  __syncthreads();
  m = redM[0];
  #pragma unroll
  for (int w = 1; w < NW; ++w) m = fmaxf(m, redM[w]);
  __syncthreads();

  // sum of exp
  float ssum = expf(v0 - m) + expf(v1 - m) + expf(v2 - m) + expf(v3 - m);
  ssum = dpp_sum64(ssum);
  if (lane == 0) redM[wave] = ssum;
  __syncthreads();
  float Z = redM[0];
  #pragma unroll
  for (int w = 1; w < NW; ++w) Z += redM[w];
  __syncthreads();

  // values: log(0.9*softmax + 0.1/N) + gumbel
  const float mixc = (float)(0.1 / (double)N);
  float4 uv = *(const float4*)(u + (size_t)b * N + iv);
  v0 = logf(0.9f * (expf(v0 - m) / Z) + mixc) + (-logf(-logf(uv.x + EPS_) + EPS_));
  v1 = logf(0.9f * (expf(v1 - m) / Z) + mixc) + (-logf(-logf(uv.y + EPS_) + EPS_));
  v2 = logf(0.9f * (expf(v2 - m) / Z) + mixc) + (-logf(-logf(uv.z + EPS_) + EPS_));
  v3 = logf(0.9f * (expf(v3 - m) / Z) + mixc) + (-logf(-logf(uv.w + EPS_) + EPS_));

  const int k = kptr[0];

  // ---- wave-local top-k (registers + shuffles only) ----
  for (int i = 0; i < k; ++i) {
    float bv = v0; int bj = 0;
    if (v1 > bv) { bv = v1; bj = 1; }
    if (v2 > bv) { bv = v2; bj = 2; }
    if (v3 > bv) { bv = v3; bj = 3; }
    int bidx = iv + bj;
    for (int s = 32; s; s >>= 1) {
      float ov = __shfl_xor(bv, s);
      int   oi = __shfl_xor(bidx, s);
      if (ov > bv || (ov == bv && oi < bidx)) { bv = ov; bidx = oi; }
    }
    if (lane == ((bidx & 255) >> 2)) {       // winner lane clears (static idx)
      int off = bidx & 3;
      if (off == 0) v0 = -FLT_MAX;
      if (off == 1) v1 = -FLT_MAX;
      if (off == 2) v2 = -FLT_MAX;
      if (off == 3) v3 = -FLT_MAX;
    }
    if (lane == 0) { cV[wave * KMAX + i] = bv; cI[wave * KMAX + i] = bidx; }
  }
  __syncthreads();

  // ---- merge NW*k candidates on wave 0 ----
  if (wave == 0) {
    const int tot = NW * k;                  // <= 512
    float mv[8]; int mi[8];
    #pragma unroll
    for (int t = 0; t < 8; ++t) {
      int c = lane + 64 * t;
      if (c < tot) {
        int w = c / k, i = c % k;
        mv[t] = cV[w * KMAX + i]; mi[t] = cI[w * KMAX + i];
      } else { mv[t] = -FLT_MAX; mi[t] = INT_MAX; }
    }
    for (int i = 0; i < k; ++i) {
      float bv = mv[0]; int bidx = mi[0];
      #pragma unroll
      for (int t = 1; t < 8; ++t)
        if (mv[t] > bv || (mv[t] == bv && mi[t] < bidx)) { bv = mv[t]; bidx = mi[t]; }
      for (int s = 32; s; s >>= 1) {
        float ov = __shfl_xor(bv, s);
        int   oi = __shfl_xor(bidx, s);
        if (ov > bv || (ov == bv && oi < bidx)) { bv = ov; bidx = oi; }
      }
      #pragma unroll
      for (int t = 0; t < 8; ++t) if (mi[t] == bidx) mv[t] = -FLT_MAX;
      if (lane == 0) out[(size_t)b * k + i] = bidx;
    }
  }
}

// =============== fallback: generic fused kernel (R1 structure) ===============
constexpr int NTF = 512;
constexpr int NWF = NTF / 64;
__global__ __launch_bounds__(NTF, 8) void fused_kernel(
    const float* __restrict__ target, const float* __restrict__ cand,
    const float* __restrict__ Wq, const float* __restrict__ bq,
    const float* __restrict__ Wk, const float* __restrict__ u,
    const int* __restrict__ kptr, int* __restrict__ out, int N)
{
  extern __shared__ float sS[];
  __shared__ float sTgt[D];
  __shared__ float sQ[D];
  __shared__ float sQt[D];
  __shared__ float redV[NWF];
  __shared__ int   redI[NWF];

  const int b = blockIdx.x, tid = threadIdx.x;
  const int lane = tid & 63, wave = tid >> 6;

  if (tid < D) sTgt[tid] = target[(size_t)b * D + tid];
  __syncthreads();
  if (tid < D) {
    float acc = 0.f;
    const float* wrow = Wq + (size_t)tid * D;
    #pragma unroll 8
    for (int e = 0; e < D; ++e) acc += sTgt[e] * wrow[e];
    sQ[tid] = acc + bq[tid];
  }
  __syncthreads();
  if (tid < D) {
    float acc = 0.f;
    #pragma unroll 8
    for (int d = 0; d < D; ++d) acc += sQ[d] * Wk[(size_t)d * D + tid];
    sQt[tid] = acc;
  }
  __syncthreads();

  const int grp = lane >> 4, gl = lane & 15;
  float q0 = sQt[gl*8+0], q1 = sQt[gl*8+1], q2 = sQt[gl*8+2], q3 = sQt[gl*8+3];
  float q4 = sQt[gl*8+4], q5 = sQt[gl*8+5], q6 = sQt[gl*8+6], q7 = sQt[gl*8+7];
  const float scale = sqrtf((float)D);
  const int rstride = NWF * 4;
  int n = wave * 4 + grp;
  for (; n + rstride < N; n += 2 * rstride) {
    const float4* r0 = (const float4*)(cand + ((size_t)b * N + n) * D);
    const float4* r1 = (const float4*)(cand + ((size_t)b * N + n + rstride) * D);
    float4 a0 = r0[gl*2+0], a1 = r0[gl*2+1], c0 = r1[gl*2+0], c1 = r1[gl*2+1];
    float p0 = a0.x*q0 + a0.y*q1 + a0.z*q2 + a0.w*q3 + a1.x*q4 + a1.y*q5 + a1.z*q6 + a1.w*q7;
    float p1 = c0.x*q0 + c0.y*q1 + c0.z*q2 + c0.w*q3 + c1.x*q4 + c1.y*q5 + c1.z*q6 + c1.w*q7;
    p0 += __shfl_xor(p0,1); p1 += __shfl_xor(p1,1);
    p0 += __shfl_xor(p0,2); p1 += __shfl_xor(p1,2);
    p0 += __shfl_xor(p0,4); p1 += __shfl_xor(p1,4);
    p0 += __shfl_xor(p0,8); p1 += __shfl_xor(p1,8);
    if (gl == 0) { sS[n] = p0 / scale; sS[n + rstride] = p1 / scale; }
  }
  if (n < N) {
    const float4* r0 = (const float4*)(cand + ((size_t)b * N + n) * D);
    float4 a0 = r0[gl*2+0], a1 = r0[gl*2+1];
    float p0 = a0.x*q0 + a0.y*q1 + a0.z*q2 + a0.w*q3 + a1.x*q4 + a1.y*q5 + a1.z*q6 + a1.w*q7;
    p0 += __shfl_xor(p0,1); p0 += __shfl_xor(p0,2); p0 += __shfl_xor(p0,4); p0 += __shfl_xor(p0,8);
    if (gl == 0) sS[n] = p0 / scale;
  }
  __syncthreads();

  float m = -FLT_MAX;
  for (int i = tid; i < N; i += NTF) m = fmaxf(m, sS[i]);
  for (int s = 32; s; s >>= 1) m = fmaxf(m, __shfl_xor(m, s));
  if (lane == 0) redV[wave] = m;
  __syncthreads();
  m = redV[0];
  #pragma unroll
  for (int w = 1; w < NWF; ++w) m = fmaxf(m, redV[w]);
  __syncthreads();

  float ssum = 0.f;
  for (int i = tid; i < N; i += NTF) ssum += expf(sS[i] - m);
  for (int s = 32; s; s >>= 1) ssum += __shfl_xor(ssum, s);
  if (lane == 0) redV[wave] = ssum;
  __syncthreads();
  float Z = redV[0];
  #pragma unroll
  for (int w = 1; w < NWF; ++w) Z += redV[w];
  __syncthreads();

  const float mixc = (float)(0.1 / (double)N);
  for (int i = tid; i < N; i += NTF) {
    float pmix = 0.9f * (expf(sS[i] - m) / Z) + mixc;
    float uvs = u[(size_t)b * N + i];
    float g = -logf(-logf(uvs + EPS_) + EPS_);
    sS[i] = logf(pmix) + g;
  }
  __syncthreads();

  const int k = kptr[0];
  for (int i = 0; i < k; ++i) {
    float bv = -FLT_MAX; int bi = N;
    for (int j = tid; j < N; j += NTF) {
      float vv = sS[j];
      if (vv > bv || (vv == bv && j < bi)) { bv = vv; bi = j; }
    }
    for (int s = 32; s; s >>= 1) {
      float ov = __shfl_xor(bv, s); int oi = __shfl_xor(bi, s);
      if (ov > bv || (ov == bv && oi < bi)) { bv = ov; bi = oi; }
    }
    if (lane == 0) { redV[wave] = bv; redI[wave] = bi; }
    __syncthreads();
    if (tid == 0) {
      float fv = redV[0]; int fi = redI[0];
      #pragma unroll
      for (int w = 1; w < NWF; ++w)
        if (redV[w] > fv || (redV[w] == fv && redI[w] < fi)) { fv = redV[w]; fi = redI[w]; }
      out[(size_t)b * k + i] = fi;
      sS[fi] = -FLT_MAX;
    }
    __syncthreads();
  }
}

extern "C" void kernel_launch(void* const* d_in, const int* in_sizes, int n_in,
                              void* d_out, int out_size, void* d_ws, size_t ws_size,
                              hipStream_t stream) {
  const float* target = (const float*)d_in[0];
  const float* cand   = (const float*)d_in[1];
  const float* Wq     = (const float*)d_in[2];
  const float* bq     = (const float*)d_in[3];
  const float* Wk     = (const float*)d_in[4];
  const float* bk     = (const float*)d_in[5];  // cancels in softmax
  const float* u      = (const float*)d_in[6];
  const int*   kptr   = (const int*)d_in[7];
  (void)bk; (void)n_in; (void)d_ws; (void)ws_size;

  const int B = in_sizes[0] / D;
  const int N = in_sizes[1] / (B * D);
  const int k = out_size / B;

  if (N == NT * 4 && (N % 64) == 0 && k <= KMAX) {
    fused2_kernel<<<B, NT, N * sizeof(float), stream>>>(
        target, cand, Wq, bq, Wk, u, kptr, (int*)d_out, N);
  } else {
    fused_kernel<<<B, NTF, N * sizeof(float), stream>>>(
        target, cand, Wq, bq, Wk, u, kptr, (int*)d_out, N);
  }
}

// Round 6
// 226.672 us; speedup vs baseline: 1.1958x; 1.0848x over previous
//
#include <hip/hip_runtime.h>
#include <cmath>
#include <cfloat>
#include <climits>

constexpr int D    = 128;
constexpr int NT   = 512;          // 8 waves
constexpr int NW   = NT / 64;
constexpr int KMAX = 64;
constexpr float EPS_ = 1e-10f;

// ---------- nontemporal float4 load ----------
typedef float vf4 __attribute__((ext_vector_type(4)));
__device__ __forceinline__ float4 ntload(const float4* p) {
  vf4 v = __builtin_nontemporal_load((const vf4*)p);
  return make_float4(v.x, v.y, v.z, v.w);
}

// ---------- DPP helpers (VALU-only cross-lane) ----------
template <int CTRL>
__device__ __forceinline__ float dpp_add(float x) {
  int y = __builtin_amdgcn_update_dpp(0, __float_as_int(x), CTRL, 0xf, 0xf, false);
  return x + __int_as_float(y);
}
template <int CTRL>
__device__ __forceinline__ float dpp_max(float x) {
  int y = __builtin_amdgcn_update_dpp(__float_as_int(x), __float_as_int(x),
                                      CTRL, 0xf, 0xf, false);
  return fmaxf(x, __int_as_float(y));
}
__device__ __forceinline__ float dpp_sum32(float x) {
  x = dpp_add<0x111>(x);
  x = dpp_add<0x112>(x);
  x = dpp_add<0x114>(x);
  x = dpp_add<0x118>(x);
  x = dpp_add<0x142>(x);
  return x;                        // valid in lanes 31 and 63
}
__device__ __forceinline__ float dpp_sum64(float x) {
  x = dpp_sum32(x);
  x = dpp_add<0x143>(x);
  return __int_as_float(__builtin_amdgcn_readlane(__float_as_int(x), 63));
}
__device__ __forceinline__ float dpp_max64(float x) {
  x = dpp_max<0x111>(x);
  x = dpp_max<0x112>(x);
  x = dpp_max<0x114>(x);
  x = dpp_max<0x118>(x);
  x = dpp_max<0x142>(x);
  x = dpp_max<0x143>(x);
  return __int_as_float(__builtin_amdgcn_readlane(__float_as_int(x), 63));
}

// ================= specialized fused kernel: N == NT*4 =================
__global__ __launch_bounds__(NT, 6) void fused2_kernel(
    const float* __restrict__ target, const float* __restrict__ cand,
    const float* __restrict__ Wq, const float* __restrict__ bq,
    const float* __restrict__ Wk, const float* __restrict__ u,
    const int* __restrict__ kptr, int* __restrict__ out, int N)
{
  extern __shared__ __align__(16) float sS[];   // N floats
  __shared__ __align__(16) float sTgt[D];
  __shared__ __align__(16) float sQ[D];
  __shared__ __align__(16) float sQt[D];
  __shared__ float redM[NW];
  __shared__ float cV[NW * KMAX];
  __shared__ int   cI[NW * KMAX];

  const int b    = blockIdx.x;
  const int tid  = threadIdx.x;
  const int lane = tid & 63;
  const int wave = tid >> 6;

  // ---- projections: qt = Wk^T (Wq t + bq); bk cancels in softmax ----
  if (tid < D) sTgt[tid] = target[(size_t)b * D + tid];
  __syncthreads();
  if (tid < D) {
    float acc = 0.f;
    const float* wrow = Wq + (size_t)tid * D;
    #pragma unroll 8
    for (int e = 0; e < D; ++e) acc += sTgt[e] * wrow[e];
    sQ[tid] = acc + bq[tid];
  }
  __syncthreads();
  if (tid < D) {
    float acc = 0.f;
    #pragma unroll 8
    for (int d = 0; d < D; ++d) acc += sQ[d] * Wk[(size_t)d * D + tid];
    sQt[tid] = acc;
  }
  __syncthreads();

  // ---- sweep: software-pipelined, block-phase-rotated, nontemporal ----
  const int p    = lane & 31;
  const int half = lane >> 5;
  const float4 qf = ((const float4*)sQt)[p];
  const float inv_scale = 1.0f / sqrtf((float)D);
  const float4* cb4 = (const float4*)(cand + (size_t)b * N * D);
  const bool writer = (p == 31);

  const int SLOTS = N / 8;                  // 256 (8 rows per slot)
  const int ITERS = SLOTS / NW;             // 32, even
  const int rot   = (b * 97) & (SLOTS - 1); // bijective per-block phase rotation

  int slotA = (wave + rot) & (SLOTS - 1);
  const float4* pA = cb4 + (size_t)slotA * 256 + lane;
  float4 A0 = ntload(pA), A1 = ntload(pA + 64), A2 = ntload(pA + 128), A3 = ntload(pA + 192);

  for (int i = 0; i < ITERS; i += 2) {
    // issue loads for iteration i+1 (B buffer) before computing A
    const int slotB = (wave + NW * (i + 1) + rot) & (SLOTS - 1);
    const float4* pB = cb4 + (size_t)slotB * 256 + lane;
    float4 B0 = ntload(pB), B1 = ntload(pB + 64), B2 = ntload(pB + 128), B3 = ntload(pB + 192);

    // compute A (slotA)
    {
      float s0 = A0.x * qf.x + A0.y * qf.y + A0.z * qf.z + A0.w * qf.w;
      float s1 = A1.x * qf.x + A1.y * qf.y + A1.z * qf.z + A1.w * qf.w;
      float s2 = A2.x * qf.x + A2.y * qf.y + A2.z * qf.z + A2.w * qf.w;
      float s3 = A3.x * qf.x + A3.y * qf.y + A3.z * qf.z + A3.w * qf.w;
      s0 = dpp_sum32(s0); s1 = dpp_sum32(s1); s2 = dpp_sum32(s2); s3 = dpp_sum32(s3);
      const int n0 = slotA * 8;
      if (writer) {
        sS[n0 + 0 + half] = s0 * inv_scale;
        sS[n0 + 2 + half] = s1 * inv_scale;
        sS[n0 + 4 + half] = s2 * inv_scale;
        sS[n0 + 6 + half] = s3 * inv_scale;
      }
    }

    // issue loads for iteration i+2 (A buffer)
    const int slotA2 = (wave + NW * (i + 2) + rot) & (SLOTS - 1);
    if (i + 2 < ITERS) {
      const float4* pA2 = cb4 + (size_t)slotA2 * 256 + lane;
      A0 = ntload(pA2); A1 = ntload(pA2 + 64); A2 = ntload(pA2 + 128); A3 = ntload(pA2 + 192);
    }

    // compute B (slotB)
    {
      float s0 = B0.x * qf.x + B0.y * qf.y + B0.z * qf.z + B0.w * qf.w;
      float s1 = B1.x * qf.x + B1.y * qf.y + B1.z * qf.z + B1.w * qf.w;
      float s2 = B2.x * qf.x + B2.y * qf.y + B2.z * qf.z + B2.w * qf.w;
      float s3 = B3.x * qf.x + B3.y * qf.y + B3.z * qf.z + B3.w * qf.w;
      s0 = dpp_sum32(s0); s1 = dpp_sum32(s1); s2 = dpp_sum32(s2); s3 = dpp_sum32(s3);
      const int n0 = slotB * 8;
      if (writer) {
        sS[n0 + 0 + half] = s0 * inv_scale;
        sS[n0 + 2 + half] = s1 * inv_scale;
        sS[n0 + 4 + half] = s2 * inv_scale;
        sS[n0 + 6 + half] = s3 * inv_scale;
      }
    }
    slotA = slotA2;
  }
  __syncthreads();

  // ---- each thread owns 4 contiguous values ----
  const int iv = wave * 256 + lane * 4;
  float4 sv = *(const float4*)(sS + iv);
  float v0 = sv.x, v1 = sv.y, v2 = sv.z, v3 = sv.w;

  // row max
  float m = fmaxf(fmaxf(v0, v1), fmaxf(v2, v3));
  m = dpp_max64(m);
  if (lane == 0) redM[wave] = m;
  __syncthreads();
  m = redM[0];
  #pragma unroll
  for (int w = 1; w < NW; ++w) m = fmaxf(m, redM[w]);
  __syncthreads();

  // sum of exp
  float ssum = expf(v0 - m) + expf(v1 - m) + expf(v2 - m) + expf(v3 - m);
  ssum = dpp_sum64(ssum);
  if (lane == 0) redM[wave] = ssum;
  __syncthreads();
  float Z = redM[0];
  #pragma unroll
  for (int w = 1; w < NW; ++w) Z += redM[w];
  __syncthreads();

  // values: log(0.9*softmax + 0.1/N) + gumbel
  const float mixc = (float)(0.1 / (double)N);
  float4 uv = *(const float4*)(u + (size_t)b * N + iv);
  v0 = logf(0.9f * (expf(v0 - m) / Z) + mixc) + (-logf(-logf(uv.x + EPS_) + EPS_));
  v1 = logf(0.9f * (expf(v1 - m) / Z) + mixc) + (-logf(-logf(uv.y + EPS_) + EPS_));
  v2 = logf(0.9f * (expf(v2 - m) / Z) + mixc) + (-logf(-logf(uv.z + EPS_) + EPS_));
  v3 = logf(0.9f * (expf(v3 - m) / Z) + mixc) + (-logf(-logf(uv.w + EPS_) + EPS_));

  const int k = kptr[0];

  // ---- wave-local top-k (registers + shuffles only) ----
  for (int i = 0; i < k; ++i) {
    float bv = v0; int bj = 0;
    if (v1 > bv) { bv = v1; bj = 1; }
    if (v2 > bv) { bv = v2; bj = 2; }
    if (v3 > bv) { bv = v3; bj = 3; }
    int bidx = iv + bj;
    for (int s = 32; s; s >>= 1) {
      float ov = __shfl_xor(bv, s);
      int   oi = __shfl_xor(bidx, s);
      if (ov > bv || (ov == bv && oi < bidx)) { bv = ov; bidx = oi; }
    }
    if (lane == ((bidx & 255) >> 2)) {
      int off = bidx & 3;
      if (off == 0) v0 = -FLT_MAX;
      if (off == 1) v1 = -FLT_MAX;
      if (off == 2) v2 = -FLT_MAX;
      if (off == 3) v3 = -FLT_MAX;
    }
    if (lane == 0) { cV[wave * KMAX + i] = bv; cI[wave * KMAX + i] = bidx; }
  }
  __syncthreads();

  // ---- merge NW*k candidates on wave 0 ----
  if (wave == 0) {
    const int tot = NW * k;
    float mv[8]; int mi[8];
    #pragma unroll
    for (int t = 0; t < 8; ++t) {
      int c = lane + 64 * t;
      if (c < tot) {
        int w = c / k, i = c % k;
        mv[t] = cV[w * KMAX + i]; mi[t] = cI[w * KMAX + i];
      } else { mv[t] = -FLT_MAX; mi[t] = INT_MAX; }
    }
    for (int i = 0; i < k; ++i) {
      float bv = mv[0]; int bidx = mi[0];
      #pragma unroll
      for (int t = 1; t < 8; ++t)
        if (mv[t] > bv || (mv[t] == bv && mi[t] < bidx)) { bv = mv[t]; bidx = mi[t]; }
      for (int s = 32; s; s >>= 1) {
        float ov = __shfl_xor(bv, s);
        int   oi = __shfl_xor(bidx, s);
        if (ov > bv || (ov == bv && oi < bidx)) { bv = ov; bidx = oi; }
      }
      #pragma unroll
      for (int t = 0; t < 8; ++t) if (mi[t] == bidx) mv[t] = -FLT_MAX;
      if (lane == 0) out[(size_t)b * k + i] = bidx;
    }
  }
}

// =============== fallback: generic fused kernel (R1 structure) ===============
constexpr int NTF = 512;
constexpr int NWF = NTF / 64;
__global__ __launch_bounds__(NTF, 8) void fused_kernel(
    const float* __restrict__ target, const float* __restrict__ cand,
    const float* __restrict__ Wq, const float* __restrict__ bq,
    const float* __restrict__ Wk, const float* __restrict__ u,
    const int* __restrict__ kptr, int* __restrict__ out, int N)
{
  extern __shared__ float sS[];
  __shared__ float sTgt[D];
  __shared__ float sQ[D];
  __shared__ float sQt[D];
  __shared__ float redV[NWF];
  __shared__ int   redI[NWF];

  const int b = blockIdx.x, tid = threadIdx.x;
  const int lane = tid & 63, wave = tid >> 6;

  if (tid < D) sTgt[tid] = target[(size_t)b * D + tid];
  __syncthreads();
  if (tid < D) {
    float acc = 0.f;
    const float* wrow = Wq + (size_t)tid * D;
    #pragma unroll 8
    for (int e = 0; e < D; ++e) acc += sTgt[e] * wrow[e];
    sQ[tid] = acc + bq[tid];
  }
  __syncthreads();
  if (tid < D) {
    float acc = 0.f;
    #pragma unroll 8
    for (int d = 0; d < D; ++d) acc += sQ[d] * Wk[(size_t)d * D + tid];
    sQt[tid] = acc;
  }
  __syncthreads();

  const int grp = lane >> 4, gl = lane & 15;
  float q0 = sQt[gl*8+0], q1 = sQt[gl*8+1], q2 = sQt[gl*8+2], q3 = sQt[gl*8+3];
  float q4 = sQt[gl*8+4], q5 = sQt[gl*8+5], q6 = sQt[gl*8+6], q7 = sQt[gl*8+7];
  const float scale = sqrtf((float)D);
  const int rstride = NWF * 4;
  int n = wave * 4 + grp;
  for (; n + rstride < N; n += 2 * rstride) {
    const float4* r0 = (const float4*)(cand + ((size_t)b * N + n) * D);
    const float4* r1 = (const float4*)(cand + ((size_t)b * N + n + rstride) * D);
    float4 a0 = r0[gl*2+0], a1 = r0[gl*2+1], c0 = r1[gl*2+0], c1 = r1[gl*2+1];
    float p0 = a0.x*q0 + a0.y*q1 + a0.z*q2 + a0.w*q3 + a1.x*q4 + a1.y*q5 + a1.z*q6 + a1.w*q7;
    float p1 = c0.x*q0 + c0.y*q1 + c0.z*q2 + c0.w*q3 + c1.x*q4 + c1.y*q5 + c1.z*q6 + c1.w*q7;
    p0 += __shfl_xor(p0,1); p1 += __shfl_xor(p1,1);
    p0 += __shfl_xor(p0,2); p1 += __shfl_xor(p1,2);
    p0 += __shfl_xor(p0,4); p1 += __shfl_xor(p1,4);
    p0 += __shfl_xor(p0,8); p1 += __shfl_xor(p1,8);
    if (gl == 0) { sS[n] = p0 / scale; sS[n + rstride] = p1 / scale; }
  }
  if (n < N) {
    const float4* r0 = (const float4*)(cand + ((size_t)b * N + n) * D);
    float4 a0 = r0[gl*2+0], a1 = r0[gl*2+1];
    float p0 = a0.x*q0 + a0.y*q1 + a0.z*q2 + a0.w*q3 + a1.x*q4 + a1.y*q5 + a1.z*q6 + a1.w*q7;
    p0 += __shfl_xor(p0,1); p0 += __shfl_xor(p0,2); p0 += __shfl_xor(p0,4); p0 += __shfl_xor(p0,8);
    if (gl == 0) sS[n] = p0 / scale;
  }
  __syncthreads();

  float m = -FLT_MAX;
  for (int i = tid; i < N; i += NTF) m = fmaxf(m, sS[i]);
  for (int s = 32; s; s >>= 1) m = fmaxf(m, __shfl_xor(m, s));
  if (lane == 0) redV[wave] = m;
  __syncthreads();
  m = redV[0];
  #pragma unroll
  for (int w = 1; w < NWF; ++w) m = fmaxf(m, redV[w]);
  __syncthreads();

  float ssum = 0.f;
  for (int i = tid; i < N; i += NTF) ssum += expf(sS[i] - m);
  for (int s = 32; s; s >>= 1) ssum += __shfl_xor(ssum, s);
  if (lane == 0) redV[wave] = ssum;
  __syncthreads();
  float Z = redV[0];
  #pragma unroll
  for (int w = 1; w < NWF; ++w) Z += redV[w];
  __syncthreads();

  const float mixc = (float)(0.1 / (double)N);
  for (int i = tid; i < N; i += NTF) {
    float pmix = 0.9f * (expf(sS[i] - m) / Z) + mixc;
    float uvs = u[(size_t)b * N + i];
    float g = -logf(-logf(uvs + EPS_) + EPS_);
    sS[i] = logf(pmix) + g;
  }
  __syncthreads();

  const int k = kptr[0];
  for (int i = 0; i < k; ++i) {
    float bv = -FLT_MAX; int bi = N;
    for (int j = tid; j < N; j += NTF) {
      float vv = sS[j];
      if (vv > bv || (vv == bv && j < bi)) { bv = vv; bi = j; }
    }
    for (int s = 32; s; s >>= 1) {
      float ov = __shfl_xor(bv, s); int oi = __shfl_xor(bi, s);
      if (ov > bv || (ov == bv && oi < bi)) { bv = ov; bi = oi; }
    }
    if (lane == 0) { redV[wave] = bv; redI[wave] = bi; }
    __syncthreads();
    if (tid == 0) {
      float fv = redV[0]; int fi = redI[0];
      #pragma unroll
      for (int w = 1; w < NWF; ++w)
        if (redV[w] > fv || (redV[w] == fv && redI[w] < fi)) { fv = redV[w]; fi = redI[w]; }
      out[(size_t)b * k + i] = fi;
      sS[fi] = -FLT_MAX;
    }
    __syncthreads();
  }
}

extern "C" void kernel_launch(void* const* d_in, const int* in_sizes, int n_in,
                              void* d_out, int out_size, void* d_ws, size_t ws_size,
                              hipStream_t stream) {
  const float* target = (const float*)d_in[0];
  const float* cand   = (const float*)d_in[1];
  const float* Wq     = (const float*)d_in[2];
  const float* bq     = (const float*)d_in[3];
  const float* Wk     = (const float*)d_in[4];
  const float* bk     = (const float*)d_in[5];  // cancels in softmax
  const float* u      = (const float*)d_in[6];
  const int*   kptr   = (const int*)d_in[7];
  (void)bk; (void)n_in; (void)d_ws; (void)ws_size;

  const int B = in_sizes[0] / D;
  const int N = in_sizes[1] / (B * D);
  const int k = out_size / B;

  if (N == NT * 4 && (N % 64) == 0 && k <= KMAX) {
    fused2_kernel<<<B, NT, N * sizeof(float), stream>>>(
        target, cand, Wq, bq, Wk, u, kptr, (int*)d_out, N);
  } else {
    fused_kernel<<<B, NTF, N * sizeof(float), stream>>>(
        target, cand, Wq, bq, Wk, u, kptr, (int*)d_out, N);
  }
}